// Round 2
// baseline (18.725 us; speedup 1.0000x reference)
//
#include <hip/hip_runtime.h>
#include <hip/hip_bf16.h>

#define EPS 1e-5f

// Problem geometry (fixed by reference):
//   inp (25, 2, 128, 8, 8) fp32; n=25, c=2, s=128, hw=64
//   3200 (n,s) instances; each: InstanceNorm over (c,hw)=128 elems,
//   qkv = y @ qkv_w^T + qkv_b  (192 outs), linear attn collapses to
//   M[c][c'] = dot(q[c], k[c']) (2x2), attn[c] = v[c] + M[c][0]*v[0] + M[c][1]*v[1],
//   out = attn @ proj_w^T + proj_b + inp (residual).  Output dtype: float32.
//
// One 64-thread wave handles I=4 consecutive instances (same n, s0..s0+3):
// weight rows live in registers and are reused 8x (4 inst x 2 chan).

#define I_PER_BLK 4

__global__ __launch_bounds__(64)
void attn_fused(const float* __restrict__ inp,
                const float* __restrict__ qkv_w,
                const float* __restrict__ qkv_b,
                const float* __restrict__ proj_w,
                const float* __restrict__ proj_b,
                float* __restrict__ out)
{
    const int t  = threadIdx.x;              // 0..63 (= hw column / output col)
    const int g0 = blockIdx.x * I_PER_BLK;   // first global instance id
    const int n  = g0 >> 7;                  // g / 128
    const int s0 = g0 & 127;                 // g % 128  (4 instances never cross n)

    __shared__ float y_lds[I_PER_BLK][2][64];
    __shared__ float a_lds[I_PER_BLK][2][64];

    // ---------------- Phase A: load + InstanceNorm ----------------
    // inp flat index: ((n*2 + c)*128 + s)*64 + j = n*16384 + c*8192 + s*64 + j
    const int base = n * 16384 + s0 * 64 + t;

    float x[I_PER_BLK][2];
    #pragma unroll
    for (int i = 0; i < I_PER_BLK; ++i) {
        x[i][0] = inp[base + i * 64];
        x[i][1] = inp[base + i * 64 + 8192];
    }

    float s1[I_PER_BLK], s2[I_PER_BLK];
    #pragma unroll
    for (int i = 0; i < I_PER_BLK; ++i) {
        s1[i] = x[i][0] + x[i][1];
        s2[i] = fmaf(x[i][0], x[i][0], x[i][1] * x[i][1]);
    }
    #pragma unroll
    for (int m = 32; m >= 1; m >>= 1) {
        #pragma unroll
        for (int i = 0; i < I_PER_BLK; ++i) {
            s1[i] += __shfl_xor(s1[i], m);
            s2[i] += __shfl_xor(s2[i], m);
        }
    }
    #pragma unroll
    for (int i = 0; i < I_PER_BLK; ++i) {
        const float mean = s1[i] * (1.0f / 128.0f);
        const float var  = s2[i] * (1.0f / 128.0f) - mean * mean;  // biased, like jnp.var
        const float r    = rsqrtf(var + EPS);
        y_lds[i][0][t] = (x[i][0] - mean) * r;
        y_lds[i][1][t] = (x[i][1] - mean) * r;
    }
    __syncthreads();

    // ---------------- Phase B: qkv = y @ qkv_w^T + qkv_b ----------------
    // thread t owns output columns: q -> o=t, k -> o=64+t, v -> o=128+t
    float aq[I_PER_BLK][2], ak[I_PER_BLK][2], av[I_PER_BLK][2];
    #pragma unroll
    for (int i = 0; i < I_PER_BLK; ++i)
        aq[i][0] = aq[i][1] = ak[i][0] = ak[i][1] = av[i][0] = av[i][1] = 0.0f;

    const float4* qr = reinterpret_cast<const float4*>(qkv_w + (      t) * 64);
    const float4* kr = reinterpret_cast<const float4*>(qkv_w + ( 64 + t) * 64);
    const float4* vr = reinterpret_cast<const float4*>(qkv_w + (128 + t) * 64);

    #pragma unroll 4
    for (int j4 = 0; j4 < 16; ++j4) {
        const float4 wq = qr[j4];
        const float4 wk = kr[j4];
        const float4 wv = vr[j4];
        #pragma unroll
        for (int i = 0; i < I_PER_BLK; ++i) {
            #pragma unroll
            for (int c = 0; c < 2; ++c) {
                const float4 y = *reinterpret_cast<const float4*>(&y_lds[i][c][j4 * 4]);
                aq[i][c] = fmaf(wq.x, y.x, fmaf(wq.y, y.y, fmaf(wq.z, y.z, fmaf(wq.w, y.w, aq[i][c]))));
                ak[i][c] = fmaf(wk.x, y.x, fmaf(wk.y, y.y, fmaf(wk.z, y.z, fmaf(wk.w, y.w, ak[i][c]))));
                av[i][c] = fmaf(wv.x, y.x, fmaf(wv.y, y.y, fmaf(wv.z, y.z, fmaf(wv.w, y.w, av[i][c]))));
            }
        }
    }

    const float bq = qkv_b[t];
    const float bk = qkv_b[64 + t];
    const float bv = qkv_b[128 + t];
    float q[I_PER_BLK][2], k[I_PER_BLK][2], v[I_PER_BLK][2];
    #pragma unroll
    for (int i = 0; i < I_PER_BLK; ++i) {
        #pragma unroll
        for (int c = 0; c < 2; ++c) {
            q[i][c] = aq[i][c] + bq;
            k[i][c] = ak[i][c] + bk;
            v[i][c] = av[i][c] + bv;
        }
    }

    // ---------------- Phase C: 2x2 M = q k^T (reduced over d=lanes) ----------------
    float p[I_PER_BLK][4];
    #pragma unroll
    for (int i = 0; i < I_PER_BLK; ++i) {
        p[i][0] = q[i][0] * k[i][0];   // M00
        p[i][1] = q[i][0] * k[i][1];   // M01
        p[i][2] = q[i][1] * k[i][0];   // M10
        p[i][3] = q[i][1] * k[i][1];   // M11
    }
    #pragma unroll
    for (int m = 32; m >= 1; m >>= 1) {
        #pragma unroll
        for (int i = 0; i < I_PER_BLK; ++i) {
            #pragma unroll
            for (int z = 0; z < 4; ++z) p[i][z] += __shfl_xor(p[i][z], m);
        }
    }
    // attn[c][e] = v[c][e] + M[c][0]*v[0][e] + M[c][1]*v[1][e]
    #pragma unroll
    for (int i = 0; i < I_PER_BLK; ++i) {
        a_lds[i][0][t] = v[i][0] + fmaf(p[i][0], v[i][0], p[i][1] * v[i][1]);
        a_lds[i][1][t] = v[i][1] + fmaf(p[i][2], v[i][0], p[i][3] * v[i][1]);
    }
    __syncthreads();

    // ---------------- Phase D: proj + residual + fp32 store ----------------
    float ao[I_PER_BLK][2];
    #pragma unroll
    for (int i = 0; i < I_PER_BLK; ++i) ao[i][0] = ao[i][1] = 0.0f;

    const float4* pr = reinterpret_cast<const float4*>(proj_w + t * 64);
    #pragma unroll 4
    for (int j4 = 0; j4 < 16; ++j4) {
        const float4 w = pr[j4];
        #pragma unroll
        for (int i = 0; i < I_PER_BLK; ++i) {
            #pragma unroll
            for (int c = 0; c < 2; ++c) {
                const float4 a = *reinterpret_cast<const float4*>(&a_lds[i][c][j4 * 4]);
                ao[i][c] = fmaf(w.x, a.x, fmaf(w.y, a.y, fmaf(w.z, a.z, fmaf(w.w, a.w, ao[i][c]))));
            }
        }
    }

    const float pb = proj_b[t];
    #pragma unroll
    for (int i = 0; i < I_PER_BLK; ++i) {
        #pragma unroll
        for (int c = 0; c < 2; ++c) {
            out[base + i * 64 + c * 8192] = ao[i][c] + pb + x[i][c];
        }
    }
}

extern "C" void kernel_launch(void* const* d_in, const int* in_sizes, int n_in,
                              void* d_out, int out_size, void* d_ws, size_t ws_size,
                              hipStream_t stream) {
    const float* inp    = (const float*)d_in[0];
    const float* qkv_w  = (const float*)d_in[1];
    const float* qkv_b  = (const float*)d_in[2];
    const float* proj_w = (const float*)d_in[3];
    const float* proj_b = (const float*)d_in[4];
    float* out = (float*)d_out;

    // 3200 instances / 4 per block = 800 blocks of one 64-lane wave each
    attn_fused<<<dim3(800), dim3(64), 0, stream>>>(inp, qkv_w, qkv_b, proj_w, proj_b, out);
}